// Round 6
// baseline (318.951 us; speedup 1.0000x reference)
//
#include <hip/hip_runtime.h>
#include <hip/hip_fp16.h>

// Trilinear sampler: im [B,H,W,D,C] f32, coords [B,N,3] f32 (y,x,z), out [B,N,C] f32.
// B=2, H=W=D=128, C=2, N=H*W*D.
//
// R6: two dispatches (R4 structure — R5 proved per-batch pipelining/L3
// residency is worthless: the gather ceiling is the L2 fill-request path
// (~3.4 TB/s of random 64B line fills), not the backing store).
//  - repack: 2 z-adjacent cells per thread -> 64B contiguous nt stores
//    (perfectly coalesced), aligned float4 reads shared between the two
//    records, no edge branch. Emits per-cell 2x2x2x2ch fp16 records (32B,
//    line-aligned) so the sample pass pays exactly ONE line fill per point.
//  - sample: unchanged from R4 (at the random-fill floor).

constexpr int Hc = 128, Wc = 128, Dc = 128;
constexpr int Npts = Hc * Wc * Dc;                 // 2^21 points per batch
constexpr int CELLS = 1 << 21;                     // 128^3 cell records per batch
constexpr size_t REC_BYTES = (size_t)2 * CELLS * 32;   // 134,217,728 (both batches)
constexpr int PTS_PER_THREAD = 4;
constexpr int NTHREADS = 2 * Npts / PTS_PER_THREAD;
constexpr int BLOCK = 256;

typedef float nfloat4 __attribute__((ext_vector_type(4)));   // native vec for nt builtins

// 16-byte payload with only 8-byte alignment guarantee (fallback path)
struct __attribute__((packed, aligned(8))) f4u { float x, y, z, w; };

// ---------------- repack: im (fp32) -> per-cell 2x2x2x2ch fp16 records ----------------
// record half2 order: [y0x0z0, y0x0z1, y0x1z0, y0x1z1 | y1x0z0, y1x0z1, y1x1z0, y1x1z1],
// each half2 = (c0,c1). One thread emits cells (z0, z0+1), z0 even: 64B contiguous.
__global__ __launch_bounds__(BLOCK)
void TrilinearSampler_34059090658011_repack(const float* __restrict__ im,
                                            nfloat4* __restrict__ rec) {
    const int tid  = blockIdx.x * BLOCK + threadIdx.x;     // [0, 2^21): cell-pairs, both batches
    const int b    = tid >> 20;                            // 2^20 pairs per batch
    const int pair = tid & ((1 << 20) - 1);
    const int z0 = (pair & 63) << 1;                       // even z base
    const int x  = (pair >> 6) & 127;
    const int y  = pair >> 13;

    const float* __restrict__ imb = im + (((size_t)b << 21) << 1);
    const int y1 = ::min(y + 1, 127);
    const int x1 = ::min(x + 1, 127);
    const int z2 = ::min(z0 + 2, 127);                     // voxel for record z0+1's far plane

    const int r00 = (y  * 128 + x ) << 7;                  // voxel row bases
    const int r01 = (y  * 128 + x1) << 7;
    const int r10 = (y1 * 128 + x ) << 7;
    const int r11 = (y1 * 128 + x1) << 7;

    // per corner: voxels (z0, z0+1) as aligned float4, voxel z2 as float2
    const float4 m00 = *reinterpret_cast<const float4*>(imb + ((r00 + z0) << 1));
    const float4 m01 = *reinterpret_cast<const float4*>(imb + ((r01 + z0) << 1));
    const float4 m10 = *reinterpret_cast<const float4*>(imb + ((r10 + z0) << 1));
    const float4 m11 = *reinterpret_cast<const float4*>(imb + ((r11 + z0) << 1));
    const float2 e00 = *reinterpret_cast<const float2*>(imb + ((r00 + z2) << 1));
    const float2 e01 = *reinterpret_cast<const float2*>(imb + ((r01 + z2) << 1));
    const float2 e10 = *reinterpret_cast<const float2*>(imb + ((r10 + z2) << 1));
    const float2 e11 = *reinterpret_cast<const float2*>(imb + ((r11 + z2) << 1));

    union { __half2 h[16]; nfloat4 f[4]; } u;
    // record z0: z-pair (z0, z0+1)
    u.h[0] = __floats2half2_rn(m00.x, m00.y);  u.h[1] = __floats2half2_rn(m00.z, m00.w);
    u.h[2] = __floats2half2_rn(m01.x, m01.y);  u.h[3] = __floats2half2_rn(m01.z, m01.w);
    u.h[4] = __floats2half2_rn(m10.x, m10.y);  u.h[5] = __floats2half2_rn(m10.z, m10.w);
    u.h[6] = __floats2half2_rn(m11.x, m11.y);  u.h[7] = __floats2half2_rn(m11.z, m11.w);
    // record z0+1: z-pair (z0+1, z0+2)  (z0=126 -> (127,127); record 127 is never sampled)
    u.h[ 8] = u.h[1];  u.h[ 9] = __floats2half2_rn(e00.x, e00.y);
    u.h[10] = u.h[3];  u.h[11] = __floats2half2_rn(e01.x, e01.y);
    u.h[12] = u.h[5];  u.h[13] = __floats2half2_rn(e10.x, e10.y);
    u.h[14] = u.h[7];  u.h[15] = __floats2half2_rn(e11.x, e11.y);

    // global cell index: b*CELLS + (y<<14 | x<<7 | z0); 2 nfloat4 per record
    nfloat4* __restrict__ dst = rec + (((size_t)b << 21) + ((y << 14) | (x << 7) | z0)) * 2;
    __builtin_nontemporal_store(u.f[0], dst + 0);
    __builtin_nontemporal_store(u.f[1], dst + 1);
    __builtin_nontemporal_store(u.f[2], dst + 2);
    __builtin_nontemporal_store(u.f[3], dst + 3);
}

// ---------------- sample pass: one 32B record (one 64B line) per point ----------------
__global__ __launch_bounds__(BLOCK)
void TrilinearSampler_34059090658011_sample(const nfloat4* __restrict__ rec,
                                            const float* __restrict__ coords,
                                            float* __restrict__ out) {
    const int t = blockIdx.x * BLOCK + threadIdx.x;        // one thread = 4 points

    const nfloat4* __restrict__ c4 = reinterpret_cast<const nfloat4*>(coords);
    const nfloat4 ca = __builtin_nontemporal_load(&c4[3 * t + 0]);
    const nfloat4 cb = __builtin_nontemporal_load(&c4[3 * t + 1]);
    const nfloat4 cc = __builtin_nontemporal_load(&c4[3 * t + 2]);

    const int b = (t * PTS_PER_THREAD) >> 21;              // wave-uniform
    const nfloat4* __restrict__ rb = rec + ((size_t)b << 22);   // CELLS*2 nfloat4/batch

    const float ys[4] = {ca.x, ca.w, cb.z, cc.y};
    const float xs[4] = {ca.y, cb.x, cb.w, cc.z};
    const float zs[4] = {ca.z, cb.y, cc.x, cc.w};

    // phase 1: cells + weights
    int   cidx[4];
    float dxs[4], dys[4], dzs[4];
#pragma unroll
    for (int i = 0; i < 4; ++i) {
        const float x = xs[i] + 1.0f;
        const float y = ys[i] + 1.0f;
        const float z = zs[i] + 1.0f;
        const int x0 = (int)floorf(x);
        const int y0 = (int)floorf(y);
        const int z0 = (int)floorf(z);
        dxs[i] = (float)(x0 + 1) - x;                      // interior guaranteed
        dys[i] = (float)(y0 + 1) - y;
        dzs[i] = (float)(z0 + 1) - z;
        const int ix0 = ::min(::max(x0 - 1, 0), Wc - 2);
        const int iy0 = ::min(::max(y0 - 1, 0), Hc - 2);
        const int izb = ::min(::max(z0 - 1, 0), Dc - 2);
        cidx[i] = ((iy0 << 7) | ix0) << 7 | izb;
    }

    // phase 2: 8 loads (2 per point, same 64B line)
    nfloat4 lo[4], hi[4];
#pragma unroll
    for (int i = 0; i < 4; ++i) {
        lo[i] = rb[(size_t)cidx[i] * 2 + 0];
        hi[i] = rb[(size_t)cidx[i] * 2 + 1];
    }

    // phase 3: combine
    float res[8];
#pragma unroll
    for (int i = 0; i < 4; ++i) {
        const __half2* h = reinterpret_cast<const __half2*>(&lo[i]);   // records 0..3
        const __half2* g = reinterpret_cast<const __half2*>(&hi[i]);   // records 4..7
        const float2 f0 = __half22float2(h[0]);   // y0 x0 z0
        const float2 f1 = __half22float2(h[1]);   // y0 x0 z1
        const float2 f2 = __half22float2(h[2]);   // y0 x1 z0
        const float2 f3 = __half22float2(h[3]);   // y0 x1 z1
        const float2 f4 = __half22float2(g[0]);   // y1 x0 z0
        const float2 f5 = __half22float2(g[1]);   // y1 x0 z1
        const float2 f6 = __half22float2(g[2]);   // y1 x1 z0
        const float2 f7 = __half22float2(g[3]);   // y1 x1 z1

        const float dx = dxs[i], dy = dys[i], dz = dzs[i];
        const float w00 = dy * dx,          w01 = dy * (1.0f - dx);
        const float w10 = (1.0f - dy) * dx, w11 = (1.0f - dy) * (1.0f - dx);
        const float wz0 = dz, wz1 = 1.0f - dz;

        const float a0 = w00 * f0.x + w01 * f2.x + w10 * f4.x + w11 * f6.x;  // z0, c0
        const float b0 = w00 * f0.y + w01 * f2.y + w10 * f4.y + w11 * f6.y;  // z0, c1
        const float a1 = w00 * f1.x + w01 * f3.x + w10 * f5.x + w11 * f7.x;  // z1, c0
        const float b1 = w00 * f1.y + w01 * f3.y + w10 * f5.y + w11 * f7.y;  // z1, c1

        res[2 * i + 0] = wz0 * a0 + wz1 * a1;
        res[2 * i + 1] = wz0 * b0 + wz1 * b1;
    }

    nfloat4* __restrict__ o4 = reinterpret_cast<nfloat4*>(out);
    const nfloat4 r0 = {res[0], res[1], res[2], res[3]};
    const nfloat4 r1 = {res[4], res[5], res[6], res[7]};
    __builtin_nontemporal_store(r0, &o4[2 * t + 0]);
    __builtin_nontemporal_store(r1, &o4[2 * t + 1]);
}

// ---------------- fallback (direct fp32 path, both batches) ----------------
__global__ __launch_bounds__(BLOCK)
void TrilinearSampler_34059090658011_kernel(const float* __restrict__ im,
                                            const float* __restrict__ coords,
                                            float* __restrict__ out) {
    const int t = blockIdx.x * BLOCK + threadIdx.x;

    const float4* __restrict__ c4 = reinterpret_cast<const float4*>(coords);
    const float4 ca = c4[3 * t + 0];
    const float4 cb = c4[3 * t + 1];
    const float4 cc = c4[3 * t + 2];

    const int b = (t * PTS_PER_THREAD) >> 21;
    const char* __restrict__ imb =
        reinterpret_cast<const char*>(im) + (size_t)b * (size_t)Npts * 8u;

    const float ys[4] = {ca.x, ca.w, cb.z, cc.y};
    const float xs[4] = {ca.y, cb.x, cb.w, cc.z};
    const float zs[4] = {ca.z, cb.y, cc.x, cc.w};

    int   off[16];
    float w00[4], w01[4], w10[4], w11[4], wz0[4], wz1[4];
#pragma unroll
    for (int i = 0; i < 4; ++i) {
        const float x = xs[i] + 1.0f;
        const float y = ys[i] + 1.0f;
        const float z = zs[i] + 1.0f;
        const int x0 = (int)floorf(x);
        const int y0 = (int)floorf(y);
        const int z0 = (int)floorf(z);
        const float dx = (float)(x0 + 1) - x;
        const float dy = (float)(y0 + 1) - y;
        const float dz = (float)(z0 + 1) - z;
        const int ix0 = ::min(::max(x0 - 1, 0), Wc - 2);
        const int iy0 = ::min(::max(y0 - 1, 0), Hc - 2);
        const int izb = ::min(::max(z0 - 1, 0), Dc - 2);
        w00[i] = dx * dy;
        w01[i] = dx * (1.0f - dy);
        w10[i] = (1.0f - dx) * dy;
        w11[i] = (1.0f - dx) * (1.0f - dy);
        wz0[i] = dz;
        wz1[i] = 1.0f - dz;
        const int r00 = ((iy0 * Wc + ix0) * Dc + izb) * 8;
        off[4 * i + 0] = r00;
        off[4 * i + 1] = r00 + Wc * Dc * 8;
        off[4 * i + 2] = r00 + Dc * 8;
        off[4 * i + 3] = r00 + (Wc + 1) * Dc * 8;
    }

    f4u g[16];
#pragma unroll
    for (int j = 0; j < 16; ++j)
        g[j] = *reinterpret_cast<const f4u*>(imb + off[j]);

    float res[8];
#pragma unroll
    for (int i = 0; i < 4; ++i) {
        const f4u g00 = g[4 * i + 0];
        const f4u g01 = g[4 * i + 1];
        const f4u g10 = g[4 * i + 2];
        const f4u g11 = g[4 * i + 3];
        const float az0c0 = w00[i] * g00.x + w01[i] * g01.x + w10[i] * g10.x + w11[i] * g11.x;
        const float az0c1 = w00[i] * g00.y + w01[i] * g01.y + w10[i] * g10.y + w11[i] * g11.y;
        const float az1c0 = w00[i] * g00.z + w01[i] * g01.z + w10[i] * g10.z + w11[i] * g11.z;
        const float az1c1 = w00[i] * g00.w + w01[i] * g01.w + w10[i] * g10.w + w11[i] * g11.w;
        res[2 * i + 0] = wz0[i] * az0c0 + wz1[i] * az1c0;
        res[2 * i + 1] = wz0[i] * az1c1 * 0.0f + wz0[i] * az0c1 + wz1[i] * az1c1;  // = wz0*az0c1 + wz1*az1c1
    }

    float4* __restrict__ o4 = reinterpret_cast<float4*>(out);
    o4[2 * t + 0] = make_float4(res[0], res[1], res[2], res[3]);
    o4[2 * t + 1] = make_float4(res[4], res[5], res[6], res[7]);
}

extern "C" void kernel_launch(void* const* d_in, const int* in_sizes, int n_in,
                              void* d_out, int out_size, void* d_ws, size_t ws_size,
                              hipStream_t stream) {
    const float* im     = (const float*)d_in[0];
    const float* coords = (const float*)d_in[1];
    float* out          = (float*)d_out;

    if (ws_size >= REC_BYTES) {
        nfloat4* rec = (nfloat4*)d_ws;
        TrilinearSampler_34059090658011_repack<<<dim3((1 << 21) / BLOCK), dim3(BLOCK), 0, stream>>>(im, rec);
        TrilinearSampler_34059090658011_sample<<<dim3(NTHREADS / BLOCK), dim3(BLOCK), 0, stream>>>(rec, coords, out);
    } else {
        TrilinearSampler_34059090658011_kernel<<<dim3(NTHREADS / BLOCK), dim3(BLOCK), 0, stream>>>(im, coords, out);
    }
}

// Round 7
// 219.810 us; speedup vs baseline: 1.4510x; 1.4510x over previous
//
#include <hip/hip_runtime.h>
#include <hip/hip_fp16.h>

// Trilinear sampler: im [B,H,W,D,C] f32, coords [B,N,3] f32 (y,x,z), out [B,N,C] f32.
// B=2, H=W=D=128, C=2, N=H*W*D.
//
// R7: repack rebuilt for PER-INSTRUCTION store coalescing.
//   R6 post-mortem: 4x16B nt stores at lane-stride 64B -> every lane hit a
//   different 64B line, partial-line nt flushes, WRITE_SIZE 332MB (2.5x ideal),
//   repack 144us. Coalescing is a per-instruction property.
//   R7: one thread per HALF-record (16B chunk), chunk index == tid, single nt
//   store -> lane i writes base+16*i, each wave streams 1KB of full lines.
//   Ideal WRITE_SIZE = 134MB.
// Sample pass unchanged (R4/R5 proved it sits at the random 64B-line fill
// floor ~3.4 TB/s: one line per point, independent of backing store).

constexpr int Hc = 128, Wc = 128, Dc = 128;
constexpr int Npts = Hc * Wc * Dc;                 // 2^21 points per batch
constexpr int CELLS = 1 << 21;                     // 128^3 cell records per batch
constexpr size_t REC_BYTES = (size_t)2 * CELLS * 32;   // 134,217,728 (both batches)
constexpr int PTS_PER_THREAD = 4;
constexpr int NTHREADS = 2 * Npts / PTS_PER_THREAD;
constexpr int BLOCK = 256;
constexpr int NCHUNKS = 1 << 23;                   // 2 batches * CELLS * 2 halves

typedef float nfloat4 __attribute__((ext_vector_type(4)));   // native vec for nt builtins

// 16-byte payload with only 8-byte alignment guarantee
struct __attribute__((packed, aligned(8))) f4u { float x, y, z, w; };

// ---------------- repack: im (fp32) -> per-cell 2x2x2x2ch fp16 records ----------------
// record layout (32B): half0 = y0 plane [y0x0z0, y0x0z1, y0x1z0, y0x1z1],
//                      half1 = y1 plane [y1x0z0, y1x0z1, y1x1z0, y1x1z1],
// each half2 = (c0,c1). One thread emits ONE 16B half; chunk index == tid.
__global__ __launch_bounds__(BLOCK)
void TrilinearSampler_34059090658011_repack(const float* __restrict__ im,
                                            nfloat4* __restrict__ rec) {
    const int tid = blockIdx.x * BLOCK + threadIdx.x;      // [0, 2^23)
    const int b    = tid >> 22;
    const int rem  = tid & ((1 << 22) - 1);
    const int half = rem & 1;                              // 0: y plane, 1: y+1 plane
    const int cell = rem >> 1;
    const int z = cell & 127;
    const int x = (cell >> 7) & 127;
    const int y = cell >> 14;

    // cells with x==127 / y==127 / z==127 are never sampled (sample clamps to
    // <=126); clamps below keep addresses in-bounds, content is don't-care.
    const int yh = ::min(y + half, 127);
    const int x1 = ::min(x + 1, 127);
    const int zq = ::min(z, 126);                          // f4u covers voxels (zq, zq+1)

    const float* __restrict__ imb = im + (((size_t)b << 21) << 1);
    const f4u A = *reinterpret_cast<const f4u*>(imb + (((yh * 128 + x ) * 128 + zq) << 1));
    const f4u B = *reinterpret_cast<const f4u*>(imb + (((yh * 128 + x1) * 128 + zq) << 1));

    union { __half2 h[4]; nfloat4 f; } u;
    u.h[0] = __floats2half2_rn(A.x, A.y);                  // (yh, x,  z)
    u.h[1] = __floats2half2_rn(A.z, A.w);                  // (yh, x,  z+1)
    u.h[2] = __floats2half2_rn(B.x, B.y);                  // (yh, x1, z)
    u.h[3] = __floats2half2_rn(B.z, B.w);                  // (yh, x1, z+1)

    // chunk address == tid -> lane i stores at base+16*i: full-line wave stream
    __builtin_nontemporal_store(u.f, rec + tid);
}

// ---------------- sample pass: one 32B record (one 64B line) per point ----------------
__global__ __launch_bounds__(BLOCK)
void TrilinearSampler_34059090658011_sample(const nfloat4* __restrict__ rec,
                                            const float* __restrict__ coords,
                                            float* __restrict__ out) {
    const int t = blockIdx.x * BLOCK + threadIdx.x;        // one thread = 4 points

    const nfloat4* __restrict__ c4 = reinterpret_cast<const nfloat4*>(coords);
    const nfloat4 ca = __builtin_nontemporal_load(&c4[3 * t + 0]);
    const nfloat4 cb = __builtin_nontemporal_load(&c4[3 * t + 1]);
    const nfloat4 cc = __builtin_nontemporal_load(&c4[3 * t + 2]);

    const int b = (t * PTS_PER_THREAD) >> 21;              // wave-uniform
    const nfloat4* __restrict__ rb = rec + ((size_t)b << 22);   // CELLS*2 nfloat4/batch

    const float ys[4] = {ca.x, ca.w, cb.z, cc.y};
    const float xs[4] = {ca.y, cb.x, cb.w, cc.z};
    const float zs[4] = {ca.z, cb.y, cc.x, cc.w};

    // phase 1: cells + weights
    int   cidx[4];
    float dxs[4], dys[4], dzs[4];
#pragma unroll
    for (int i = 0; i < 4; ++i) {
        const float x = xs[i] + 1.0f;
        const float y = ys[i] + 1.0f;
        const float z = zs[i] + 1.0f;
        const int x0 = (int)floorf(x);
        const int y0 = (int)floorf(y);
        const int z0 = (int)floorf(z);
        dxs[i] = (float)(x0 + 1) - x;                      // interior guaranteed
        dys[i] = (float)(y0 + 1) - y;
        dzs[i] = (float)(z0 + 1) - z;
        const int ix0 = ::min(::max(x0 - 1, 0), Wc - 2);
        const int iy0 = ::min(::max(y0 - 1, 0), Hc - 2);
        const int izb = ::min(::max(z0 - 1, 0), Dc - 2);
        cidx[i] = ((iy0 << 7) | ix0) << 7 | izb;
    }

    // phase 2: 8 loads (2 per point, same 64B line)
    nfloat4 lo[4], hi[4];
#pragma unroll
    for (int i = 0; i < 4; ++i) {
        lo[i] = rb[(size_t)cidx[i] * 2 + 0];
        hi[i] = rb[(size_t)cidx[i] * 2 + 1];
    }

    // phase 3: combine
    float res[8];
#pragma unroll
    for (int i = 0; i < 4; ++i) {
        const __half2* h = reinterpret_cast<const __half2*>(&lo[i]);   // y0 plane
        const __half2* g = reinterpret_cast<const __half2*>(&hi[i]);   // y1 plane
        const float2 f0 = __half22float2(h[0]);   // y0 x0 z0
        const float2 f1 = __half22float2(h[1]);   // y0 x0 z1
        const float2 f2 = __half22float2(h[2]);   // y0 x1 z0
        const float2 f3 = __half22float2(h[3]);   // y0 x1 z1
        const float2 f4 = __half22float2(g[0]);   // y1 x0 z0
        const float2 f5 = __half22float2(g[1]);   // y1 x0 z1
        const float2 f6 = __half22float2(g[2]);   // y1 x1 z0
        const float2 f7 = __half22float2(g[3]);   // y1 x1 z1

        const float dx = dxs[i], dy = dys[i], dz = dzs[i];
        const float w00 = dy * dx,          w01 = dy * (1.0f - dx);
        const float w10 = (1.0f - dy) * dx, w11 = (1.0f - dy) * (1.0f - dx);
        const float wz0 = dz, wz1 = 1.0f - dz;

        const float a0 = w00 * f0.x + w01 * f2.x + w10 * f4.x + w11 * f6.x;  // z0, c0
        const float b0 = w00 * f0.y + w01 * f2.y + w10 * f4.y + w11 * f6.y;  // z0, c1
        const float a1 = w00 * f1.x + w01 * f3.x + w10 * f5.x + w11 * f7.x;  // z1, c0
        const float b1 = w00 * f1.y + w01 * f3.y + w10 * f5.y + w11 * f7.y;  // z1, c1

        res[2 * i + 0] = wz0 * a0 + wz1 * a1;
        res[2 * i + 1] = wz0 * b0 + wz1 * b1;
    }

    nfloat4* __restrict__ o4 = reinterpret_cast<nfloat4*>(out);
    const nfloat4 r0 = {res[0], res[1], res[2], res[3]};
    const nfloat4 r1 = {res[4], res[5], res[6], res[7]};
    __builtin_nontemporal_store(r0, &o4[2 * t + 0]);
    __builtin_nontemporal_store(r1, &o4[2 * t + 1]);
}

// ---------------- fallback (direct fp32 path, both batches) ----------------
__global__ __launch_bounds__(BLOCK)
void TrilinearSampler_34059090658011_kernel(const float* __restrict__ im,
                                            const float* __restrict__ coords,
                                            float* __restrict__ out) {
    const int t = blockIdx.x * BLOCK + threadIdx.x;

    const float4* __restrict__ c4 = reinterpret_cast<const float4*>(coords);
    const float4 ca = c4[3 * t + 0];
    const float4 cb = c4[3 * t + 1];
    const float4 cc = c4[3 * t + 2];

    const int b = (t * PTS_PER_THREAD) >> 21;
    const char* __restrict__ imb =
        reinterpret_cast<const char*>(im) + (size_t)b * (size_t)Npts * 8u;

    const float ys[4] = {ca.x, ca.w, cb.z, cc.y};
    const float xs[4] = {ca.y, cb.x, cb.w, cc.z};
    const float zs[4] = {ca.z, cb.y, cc.x, cc.w};

    int   off[16];
    float w00[4], w01[4], w10[4], w11[4], wz0[4], wz1[4];
#pragma unroll
    for (int i = 0; i < 4; ++i) {
        const float x = xs[i] + 1.0f;
        const float y = ys[i] + 1.0f;
        const float z = zs[i] + 1.0f;
        const int x0 = (int)floorf(x);
        const int y0 = (int)floorf(y);
        const int z0 = (int)floorf(z);
        const float dx = (float)(x0 + 1) - x;
        const float dy = (float)(y0 + 1) - y;
        const float dz = (float)(z0 + 1) - z;
        const int ix0 = ::min(::max(x0 - 1, 0), Wc - 2);
        const int iy0 = ::min(::max(y0 - 1, 0), Hc - 2);
        const int izb = ::min(::max(z0 - 1, 0), Dc - 2);
        w00[i] = dx * dy;
        w01[i] = dx * (1.0f - dy);
        w10[i] = (1.0f - dx) * dy;
        w11[i] = (1.0f - dx) * (1.0f - dy);
        wz0[i] = dz;
        wz1[i] = 1.0f - dz;
        const int r00 = ((iy0 * Wc + ix0) * Dc + izb) * 8;
        off[4 * i + 0] = r00;
        off[4 * i + 1] = r00 + Wc * Dc * 8;
        off[4 * i + 2] = r00 + Dc * 8;
        off[4 * i + 3] = r00 + (Wc + 1) * Dc * 8;
    }

    f4u g[16];
#pragma unroll
    for (int j = 0; j < 16; ++j)
        g[j] = *reinterpret_cast<const f4u*>(imb + off[j]);

    float res[8];
#pragma unroll
    for (int i = 0; i < 4; ++i) {
        const f4u g00 = g[4 * i + 0];
        const f4u g01 = g[4 * i + 1];
        const f4u g10 = g[4 * i + 2];
        const f4u g11 = g[4 * i + 3];
        const float az0c0 = w00[i] * g00.x + w01[i] * g01.x + w10[i] * g10.x + w11[i] * g11.x;
        const float az0c1 = w00[i] * g00.y + w01[i] * g01.y + w10[i] * g10.y + w11[i] * g11.y;
        const float az1c0 = w00[i] * g00.z + w01[i] * g01.z + w10[i] * g10.z + w11[i] * g11.z;
        const float az1c1 = w00[i] * g00.w + w01[i] * g01.w + w10[i] * g10.w + w11[i] * g11.w;
        res[2 * i + 0] = wz0[i] * az0c0 + wz1[i] * az1c0;
        res[2 * i + 1] = wz0[i] * az0c1 + wz1[i] * az1c1;
    }

    float4* __restrict__ o4 = reinterpret_cast<float4*>(out);
    o4[2 * t + 0] = make_float4(res[0], res[1], res[2], res[3]);
    o4[2 * t + 1] = make_float4(res[4], res[5], res[6], res[7]);
}

extern "C" void kernel_launch(void* const* d_in, const int* in_sizes, int n_in,
                              void* d_out, int out_size, void* d_ws, size_t ws_size,
                              hipStream_t stream) {
    const float* im     = (const float*)d_in[0];
    const float* coords = (const float*)d_in[1];
    float* out          = (float*)d_out;

    if (ws_size >= REC_BYTES) {
        nfloat4* rec = (nfloat4*)d_ws;
        TrilinearSampler_34059090658011_repack<<<dim3(NCHUNKS / BLOCK), dim3(BLOCK), 0, stream>>>(im, rec);
        TrilinearSampler_34059090658011_sample<<<dim3(NTHREADS / BLOCK), dim3(BLOCK), 0, stream>>>(rec, coords, out);
    } else {
        TrilinearSampler_34059090658011_kernel<<<dim3(NTHREADS / BLOCK), dim3(BLOCK), 0, stream>>>(im, coords, out);
    }
}

// Round 8
// 219.591 us; speedup vs baseline: 1.4525x; 1.0010x over previous
//
#include <hip/hip_runtime.h>
#include <hip/hip_fp16.h>

// Trilinear sampler: im [B,H,W,D,C] f32, coords [B,N,3] f32 (y,x,z), out [B,N,C] f32.
// B=2, H=W=D=128, C=2, N=H*W*D.
//
// R8: LDS-staged repack.
//   R7 post-mortem: repack was TA-request-bound (2 overlapping 16B loads +
//   1 store per thread x 8.4M threads = 25M requests ~= 41us at ~1 req/cyc/CU),
//   not byte-bound (168 MB ~= 28us). R8 stages each block's 4 voxel rows into
//   LDS with ONE coalesced 16B load per thread, builds chunks from LDS, keeps
//   R7's single full-line-coalesced nt store (chunk id == tid).
//   Global requests 25M -> 16.8M.
// Sample pass unchanged: pinned at the random 64B-line fill floor
// (FETCH = N x 64B = 280 MB at ~3.5 TB/s; invariant across R1/R2/R4/R5).

constexpr int Hc = 128, Wc = 128, Dc = 128;
constexpr int Npts = Hc * Wc * Dc;                 // 2^21 points per batch
constexpr int CELLS = 1 << 21;                     // 128^3 cell records per batch
constexpr size_t REC_BYTES = (size_t)2 * CELLS * 32;   // 134,217,728 (both batches)
constexpr int PTS_PER_THREAD = 4;
constexpr int NTHREADS = 2 * Npts / PTS_PER_THREAD;
constexpr int BLOCK = 256;
constexpr int NCHUNKS = 1 << 23;                   // 2 batches * CELLS * 2 halves

typedef float nfloat4 __attribute__((ext_vector_type(4)));   // native vec for nt builtins

// 16-byte payload with only 8-byte alignment guarantee (fallback path)
struct __attribute__((packed, aligned(8))) f4u { float x, y, z, w; };

// ---------------- repack: im (fp32) -> per-cell 2x2x2x2ch fp16 records ----------------
// record layout (32B): half0 = y plane [x z, x z+1, x1 z, x1 z+1],
//                      half1 = y1 plane [same], each half2 = (c0,c1).
// Block = 256 chunks = 128 cells = one full z-row at fixed (b,y,x).
__global__ __launch_bounds__(BLOCK)
void TrilinearSampler_34059090658011_repack(const float* __restrict__ im,
                                            nfloat4* __restrict__ rec) {
    __shared__ __align__(16) float2 srow[4][128];          // rows: (y,x),(y,x1),(y1,x),(y1,x1)

    const int tid     = threadIdx.x;
    const int gchunk0 = blockIdx.x * BLOCK;                // block's first chunk (256-aligned)
    const int b       = gchunk0 >> 22;                     // 2^22 chunks per batch
    const int cell0   = (gchunk0 & ((1 << 22) - 1)) >> 1;  // first cell (z=0)
    const int x = (cell0 >> 7) & 127;
    const int y = cell0 >> 14;

    const float* __restrict__ imb = im + ((size_t)b << 22);   // 2^21 cells * 2ch floats

    // ---- stage: thread loads one 16B piece; lane-consecutive within each row ----
    const int y1v = ::min(y + 1, 127);
    const int x1v = ::min(x + 1, 127);
    const int r = tid >> 6;                                // row 0..3
    const int p = tid & 63;                                // 16B piece within row
    const int rowv = (r == 0) ? (y   * 128 + x  )
                   : (r == 1) ? (y   * 128 + x1v)
                   : (r == 2) ? (y1v * 128 + x  )
                   :            (y1v * 128 + x1v);
    const nfloat4 v = *reinterpret_cast<const nfloat4*>(imb + (size_t)rowv * 256 + p * 4);
    reinterpret_cast<nfloat4*>(&srow[r][0])[p] = v;
    __syncthreads();

    // ---- assemble: thread builds one 16B chunk (cell z, half h) ----
    const int h  = tid & 1;                                // 0: y plane, 1: y1 plane
    const int z  = tid >> 1;                               // cell z
    const int zb = ::min(z, 126);                          // z=127 cell never sampled
    const int ra = h ? 2 : 0;                              // (yh, x)
    const int rx = h ? 3 : 1;                              // (yh, x1)
    const float2 a0 = srow[ra][zb], a1 = srow[ra][zb + 1];
    const float2 b0 = srow[rx][zb], b1 = srow[rx][zb + 1];

    union { __half2 hh[4]; nfloat4 f; } u;
    u.hh[0] = __floats2half2_rn(a0.x, a0.y);               // (yh, x,  z)
    u.hh[1] = __floats2half2_rn(a1.x, a1.y);               // (yh, x,  z+1)
    u.hh[2] = __floats2half2_rn(b0.x, b0.y);               // (yh, x1, z)
    u.hh[3] = __floats2half2_rn(b1.x, b1.y);               // (yh, x1, z+1)

    // chunk address == global chunk id -> lane i stores base+16*i: full-line stream
    __builtin_nontemporal_store(u.f, rec + gchunk0 + tid);
}

// ---------------- sample pass: one 32B record (one 64B line) per point ----------------
__global__ __launch_bounds__(BLOCK)
void TrilinearSampler_34059090658011_sample(const nfloat4* __restrict__ rec,
                                            const float* __restrict__ coords,
                                            float* __restrict__ out) {
    const int t = blockIdx.x * BLOCK + threadIdx.x;        // one thread = 4 points

    const nfloat4* __restrict__ c4 = reinterpret_cast<const nfloat4*>(coords);
    const nfloat4 ca = __builtin_nontemporal_load(&c4[3 * t + 0]);
    const nfloat4 cb = __builtin_nontemporal_load(&c4[3 * t + 1]);
    const nfloat4 cc = __builtin_nontemporal_load(&c4[3 * t + 2]);

    const int b = (t * PTS_PER_THREAD) >> 21;              // wave-uniform
    const nfloat4* __restrict__ rb = rec + ((size_t)b << 22);   // CELLS*2 nfloat4/batch

    const float ys[4] = {ca.x, ca.w, cb.z, cc.y};
    const float xs[4] = {ca.y, cb.x, cb.w, cc.z};
    const float zs[4] = {ca.z, cb.y, cc.x, cc.w};

    // phase 1: cells + weights
    int   cidx[4];
    float dxs[4], dys[4], dzs[4];
#pragma unroll
    for (int i = 0; i < 4; ++i) {
        const float x = xs[i] + 1.0f;
        const float y = ys[i] + 1.0f;
        const float z = zs[i] + 1.0f;
        const int x0 = (int)floorf(x);
        const int y0 = (int)floorf(y);
        const int z0 = (int)floorf(z);
        dxs[i] = (float)(x0 + 1) - x;                      // interior guaranteed
        dys[i] = (float)(y0 + 1) - y;
        dzs[i] = (float)(z0 + 1) - z;
        const int ix0 = ::min(::max(x0 - 1, 0), Wc - 2);
        const int iy0 = ::min(::max(y0 - 1, 0), Hc - 2);
        const int izb = ::min(::max(z0 - 1, 0), Dc - 2);
        cidx[i] = ((iy0 << 7) | ix0) << 7 | izb;
    }

    // phase 2: 8 loads (2 per point, same 64B line)
    nfloat4 lo[4], hi[4];
#pragma unroll
    for (int i = 0; i < 4; ++i) {
        lo[i] = rb[(size_t)cidx[i] * 2 + 0];
        hi[i] = rb[(size_t)cidx[i] * 2 + 1];
    }

    // phase 3: combine
    float res[8];
#pragma unroll
    for (int i = 0; i < 4; ++i) {
        const __half2* h = reinterpret_cast<const __half2*>(&lo[i]);   // y0 plane
        const __half2* g = reinterpret_cast<const __half2*>(&hi[i]);   // y1 plane
        const float2 f0 = __half22float2(h[0]);   // y0 x0 z0
        const float2 f1 = __half22float2(h[1]);   // y0 x0 z1
        const float2 f2 = __half22float2(h[2]);   // y0 x1 z0
        const float2 f3 = __half22float2(h[3]);   // y0 x1 z1
        const float2 f4 = __half22float2(g[0]);   // y1 x0 z0
        const float2 f5 = __half22float2(g[1]);   // y1 x0 z1
        const float2 f6 = __half22float2(g[2]);   // y1 x1 z0
        const float2 f7 = __half22float2(g[3]);   // y1 x1 z1

        const float dx = dxs[i], dy = dys[i], dz = dzs[i];
        const float w00 = dy * dx,          w01 = dy * (1.0f - dx);
        const float w10 = (1.0f - dy) * dx, w11 = (1.0f - dy) * (1.0f - dx);
        const float wz0 = dz, wz1 = 1.0f - dz;

        const float a0 = w00 * f0.x + w01 * f2.x + w10 * f4.x + w11 * f6.x;  // z0, c0
        const float b0 = w00 * f0.y + w01 * f2.y + w10 * f4.y + w11 * f6.y;  // z0, c1
        const float a1 = w00 * f1.x + w01 * f3.x + w10 * f5.x + w11 * f7.x;  // z1, c0
        const float b1 = w00 * f1.y + w01 * f3.y + w10 * f5.y + w11 * f7.y;  // z1, c1

        res[2 * i + 0] = wz0 * a0 + wz1 * a1;
        res[2 * i + 1] = wz0 * b0 + wz1 * b1;
    }

    nfloat4* __restrict__ o4 = reinterpret_cast<nfloat4*>(out);
    const nfloat4 r0 = {res[0], res[1], res[2], res[3]};
    const nfloat4 r1 = {res[4], res[5], res[6], res[7]};
    __builtin_nontemporal_store(r0, &o4[2 * t + 0]);
    __builtin_nontemporal_store(r1, &o4[2 * t + 1]);
}

// ---------------- fallback (direct fp32 path, both batches) ----------------
__global__ __launch_bounds__(BLOCK)
void TrilinearSampler_34059090658011_kernel(const float* __restrict__ im,
                                            const float* __restrict__ coords,
                                            float* __restrict__ out) {
    const int t = blockIdx.x * BLOCK + threadIdx.x;

    const float4* __restrict__ c4 = reinterpret_cast<const float4*>(coords);
    const float4 ca = c4[3 * t + 0];
    const float4 cb = c4[3 * t + 1];
    const float4 cc = c4[3 * t + 2];

    const int b = (t * PTS_PER_THREAD) >> 21;
    const char* __restrict__ imb =
        reinterpret_cast<const char*>(im) + (size_t)b * (size_t)Npts * 8u;

    const float ys[4] = {ca.x, ca.w, cb.z, cc.y};
    const float xs[4] = {ca.y, cb.x, cb.w, cc.z};
    const float zs[4] = {ca.z, cb.y, cc.x, cc.w};

    int   off[16];
    float w00[4], w01[4], w10[4], w11[4], wz0[4], wz1[4];
#pragma unroll
    for (int i = 0; i < 4; ++i) {
        const float x = xs[i] + 1.0f;
        const float y = ys[i] + 1.0f;
        const float z = zs[i] + 1.0f;
        const int x0 = (int)floorf(x);
        const int y0 = (int)floorf(y);
        const int z0 = (int)floorf(z);
        const float dx = (float)(x0 + 1) - x;
        const float dy = (float)(y0 + 1) - y;
        const float dz = (float)(z0 + 1) - z;
        const int ix0 = ::min(::max(x0 - 1, 0), Wc - 2);
        const int iy0 = ::min(::max(y0 - 1, 0), Hc - 2);
        const int izb = ::min(::max(z0 - 1, 0), Dc - 2);
        w00[i] = dx * dy;
        w01[i] = dx * (1.0f - dy);
        w10[i] = (1.0f - dx) * dy;
        w11[i] = (1.0f - dx) * (1.0f - dy);
        wz0[i] = dz;
        wz1[i] = 1.0f - dz;
        const int r00 = ((iy0 * Wc + ix0) * Dc + izb) * 8;
        off[4 * i + 0] = r00;
        off[4 * i + 1] = r00 + Wc * Dc * 8;
        off[4 * i + 2] = r00 + Dc * 8;
        off[4 * i + 3] = r00 + (Wc + 1) * Dc * 8;
    }

    f4u g[16];
#pragma unroll
    for (int j = 0; j < 16; ++j)
        g[j] = *reinterpret_cast<const f4u*>(imb + off[j]);

    float res[8];
#pragma unroll
    for (int i = 0; i < 4; ++i) {
        const f4u g00 = g[4 * i + 0];
        const f4u g01 = g[4 * i + 1];
        const f4u g10 = g[4 * i + 2];
        const f4u g11 = g[4 * i + 3];
        const float az0c0 = w00[i] * g00.x + w01[i] * g01.x + w10[i] * g10.x + w11[i] * g11.x;
        const float az0c1 = w00[i] * g00.y + w01[i] * g01.y + w10[i] * g10.y + w11[i] * g11.y;
        const float az1c0 = w00[i] * g00.z + w01[i] * g01.z + w10[i] * g10.z + w11[i] * g11.z;
        const float az1c1 = w00[i] * g00.w + w01[i] * g01.w + w10[i] * g10.w + w11[i] * g11.w;
        res[2 * i + 0] = wz0[i] * az0c0 + wz1[i] * az1c0;
        res[2 * i + 1] = wz0[i] * az0c1 + wz1[i] * az1c1;
    }

    float4* __restrict__ o4 = reinterpret_cast<float4*>(out);
    o4[2 * t + 0] = make_float4(res[0], res[1], res[2], res[3]);
    o4[2 * t + 1] = make_float4(res[4], res[5], res[6], res[7]);
}

extern "C" void kernel_launch(void* const* d_in, const int* in_sizes, int n_in,
                              void* d_out, int out_size, void* d_ws, size_t ws_size,
                              hipStream_t stream) {
    const float* im     = (const float*)d_in[0];
    const float* coords = (const float*)d_in[1];
    float* out          = (float*)d_out;

    if (ws_size >= REC_BYTES) {
        nfloat4* rec = (nfloat4*)d_ws;
        TrilinearSampler_34059090658011_repack<<<dim3(NCHUNKS / BLOCK), dim3(BLOCK), 0, stream>>>(im, rec);
        TrilinearSampler_34059090658011_sample<<<dim3(NTHREADS / BLOCK), dim3(BLOCK), 0, stream>>>(rec, coords, out);
    } else {
        TrilinearSampler_34059090658011_kernel<<<dim3(NTHREADS / BLOCK), dim3(BLOCK), 0, stream>>>(im, coords, out);
    }
}